// Round 1
// baseline (442.601 us; speedup 1.0000x reference)
//
#include <hip/hip_runtime.h>
#include <math.h>

#define NEMB 200000
#define MM   200
#define KTOP 32
#define BB   1024
#define FEW  5
#define NROW 2058           // 2*BB + 2*FEW (row,half) tasks
#define NSLC 13             // ceil(200/16) 16-row slices
#define SIMS_BLOCKS ((NROW * NSLC + 3) / 4)   // 6689

typedef short short8 __attribute__((ext_vector_type(8)));
typedef float floatx4 __attribute__((ext_vector_type(4)));

__device__ __forceinline__ float sigf(float x) { return 1.0f / (1.0f + expf(-x)); }

__device__ __forceinline__ unsigned short f2bf(float x) {   // RNE f32->bf16
    unsigned u = __float_as_uint(x);
    unsigned r = (u + 0x7FFF + ((u >> 16) & 1)) >> 16;
    return (unsigned short)r;
}

// ---------------------------------------------------------------------------
// K_front: merged (a) sims — barrier-free, one wave per (row, slice-of-16),
// fp32 table (selection-exact); (b) weight conversion fp32->bf16 + LSTM
// gate-compaction remap + bias fold. Independent work, one launch.
// ---------------------------------------------------------------------------
__global__ __launch_bounds__(256) void front_kernel(
    const int* __restrict__ query, const int* __restrict__ support,
    const int* __restrict__ qlc, const int* __restrict__ qrc,
    const int* __restrict__ slc, const int* __restrict__ srrc,
    const float* __restrict__ emb, float* __restrict__ sims,
    const float* __restrict__ se_w1, const float* __restrict__ se_w2,
    const float* __restrict__ W_ih, const float* __restrict__ W_hh,
    const float* __restrict__ b_ih, const float* __restrict__ b_hh,
    unsigned short* __restrict__ w1b, unsigned short* __restrict__ w2b,
    unsigned short* __restrict__ wihb, unsigned short* __restrict__ whhb,
    float* __restrict__ bias_c)
{
    if (blockIdx.x < SIMS_BLOCKS) {
        const int wid  = (blockIdx.x * 256 + threadIdx.x) >> 6;
        const int lane = threadIdx.x & 63;
        const int quad = lane >> 2, ql = lane & 3;
        if (wid >= NROW * NSLC) return;

        const int rh = wid / NSLC, slice = wid - rh * NSLC;
        const int* conn; int eid;
        if (rh < BB)                 { conn = qlc + rh * (MM * 2);                 eid = query[rh * 2]; }
        else if (rh < 2 * BB)        { int b = rh - BB;        conn = qrc + b * (MM * 2);  eid = query[b * 2 + 1]; }
        else if (rh < 2 * BB + FEW)  { int r = rh - 2 * BB;    conn = slc + r * (MM * 2);  eid = support[r * 2]; }
        else                         { int r = rh - 2 * BB - FEW; conn = srrc + r * (MM * 2); eid = support[r * 2 + 1]; }

        const float4* cb = (const float4*)(emb + (size_t)eid * 128);
        float4 cr[8];
        #pragma unroll
        for (int i = 0; i < 8; ++i) cr[i] = cb[i * 4 + ql];
        float csq = 0.f;
        #pragma unroll
        for (int i = 0; i < 8; ++i)
            csq += cr[i].x * cr[i].x + cr[i].y * cr[i].y + cr[i].z * cr[i].z + cr[i].w * cr[i].w;
        csq += __shfl_xor(csq, 1, 4); csq += __shfl_xor(csq, 2, 4);
        const float cn = sqrtf(csq);

        const int  j = slice * 16 + quad;
        const bool v = j < MM;
        const int  rid = v ? conn[j * 2 + 1] : 0;
        const float4* eb = (const float4*)(emb + (size_t)rid * 128);
        float num = 0.f, sq = 0.f;
        #pragma unroll
        for (int i = 0; i < 8; ++i) {
            float4 e = eb[i * 4 + ql];
            num += cr[i].x * e.x + cr[i].y * e.y + cr[i].z * e.z + cr[i].w * e.w;
            sq  += e.x * e.x + e.y * e.y + e.z * e.z + e.w * e.w;
        }
        num += __shfl_xor(num, 1, 4); num += __shfl_xor(num, 2, 4);
        sq  += __shfl_xor(sq , 1, 4); sq  += __shfl_xor(sq , 2, 4);
        if (ql == 0 && v) sims[rh * MM + j] = num / fmaxf(cn * sqrtf(sq), 1e-8f);
        return;
    }

    int i = (blockIdx.x - SIMS_BLOCKS) * 256 + threadIdx.x;
    if (i < 131072) { w1b[i] = f2bf(se_w1[i]); return; }
    i -= 131072;
    if (i < 131072) { w2b[i] = f2bf(se_w2[i]); return; }
    i -= 131072;
    if (i < 262144) {           // W_ih compact: row n <- orig ((n>>8)<<9)|(n&255)
        int n = i >> 8, k = i & 255;
        int nb = ((n >> 8) << 9) | (n & 255);
        wihb[i] = f2bf(W_ih[(size_t)nb * 256 + k]); return;
    }
    i -= 262144;
    if (i < 524288) {
        int n = i >> 9, k = i & 511;
        int nb = ((n >> 8) << 9) | (n & 255);
        whhb[i] = f2bf(W_hh[(size_t)nb * 512 + k]); return;
    }
    i -= 524288;
    if (i < 1024) {
        int nb = ((i >> 8) << 9) | (i & 255);
        bias_c[i] = b_ih[nb] + b_hh[nb];
    }
}

// ---------------------------------------------------------------------------
// K2: rank (top-K, tie-break lower index, float4 scan) + mean gather -> avgbuf
// ---------------------------------------------------------------------------
__global__ __launch_bounds__(256) void rank_avg_kernel(
    const int* __restrict__ query, const int* __restrict__ support,
    const int* __restrict__ qlc, const int* __restrict__ qrc,
    const int* __restrict__ slc, const int* __restrict__ srrc,
    const float* __restrict__ emb, const float* __restrict__ sims,
    float* __restrict__ avgbuf)
{
    __shared__ float simsL[MM];
    __shared__ int   cids[MM];
    __shared__ int   selr[KTOP], sele[KTOP];
    __shared__ float partial[512];
    __shared__ int   nsel;

    const int t   = threadIdx.x;
    const int blk = blockIdx.x;

    const int* conn;
    if (blk < BB)                { conn = qlc + blk * (MM * 2); }
    else if (blk < 2 * BB)       { conn = qrc + (blk - BB) * (MM * 2); }
    else if (blk < 2 * BB + FEW) { conn = slc + (blk - 2 * BB) * (MM * 2); }
    else                         { conn = srrc + (blk - 2 * BB - FEW) * (MM * 2); }

    if (t < MM) { simsL[t] = sims[blk * MM + t]; cids[t] = conn[t * 2 + 1]; }
    if (t == 0) nsel = 0;
    __syncthreads();

    if (t < MM) {
        float st = simsL[t];
        int cnt = 0;
        #pragma unroll 2
        for (int j4 = 0; j4 < MM / 4; ++j4) {
            float4 s4 = *(const float4*)&simsL[j4 * 4];
            int jb = j4 * 4;
            cnt += (s4.x > st) || (s4.x == st && (jb + 0) < t);
            cnt += (s4.y > st) || (s4.y == st && (jb + 1) < t);
            cnt += (s4.z > st) || (s4.z == st && (jb + 2) < t);
            cnt += (s4.w > st) || (s4.w == st && (jb + 3) < t);
        }
        if (cnt < KTOP) {
            int p = atomicAdd(&nsel, 1);
            selr[p] = conn[t * 2 + 0];
            sele[p] = cids[t];
        }
    }
    __syncthreads();

    {
        const int slot = t & 127;
        const int hpar = t >> 7;
        const bool isEnt = slot >= 64;
        float2 acc = make_float2(0.f, 0.f);
        for (int s = hpar; s < KTOP; s += 2) {
            int rid = isEnt ? sele[s] : selr[s];
            float2 v = ((const float2*)(emb + (size_t)rid * 128))[slot & 63];
            acc.x += v.x; acc.y += v.y;
        }
        ((float2*)partial)[t] = acc;
    }
    __syncthreads();
    if (t < 128) {
        float2 a = ((float2*)partial)[t];
        float2 b = ((float2*)partial)[t + 128];
        ((float2*)(avgbuf + (size_t)blk * 256))[t] =
            make_float2((a.x + b.x) * (1.0f / KTOP), (a.y + b.y) * (1.0f / KTOP));
    }
}

// ---------------------------------------------------------------------------
// K3: GCN matvec as fp32 GEMM -> qn2 (fp32) + qn2_bf (bf16)
// ---------------------------------------------------------------------------
__global__ __launch_bounds__(256) void gcn_gemm_kernel(
    const float* __restrict__ A, const float* __restrict__ W,
    const float* __restrict__ gcn_bias, const float* __restrict__ gcn_b,
    float* __restrict__ qn2, unsigned short* __restrict__ qn2b)
{
    __shared__ float As[16][68];
    __shared__ float Ws[16][68];
    const int t  = threadIdx.x;
    const int bm = blockIdx.y * 64, bn = blockIdx.x * 64;
    const int tx = t & 15, ty = t >> 4;
    const int lrow = t >> 2, lk4 = (t & 3) * 4;

    const float* Ap = A + (size_t)(bm + lrow) * 256 + lk4;
    const float* Wp = W + (size_t)(bn + lrow) * 256 + lk4;

    float acc[4][4] = {};
    for (int k0 = 0; k0 < 256; k0 += 16) {
        float4 av = *(const float4*)(Ap + k0);
        float4 wv = *(const float4*)(Wp + k0);
        __syncthreads();
        As[lk4 + 0][lrow] = av.x; As[lk4 + 1][lrow] = av.y;
        As[lk4 + 2][lrow] = av.z; As[lk4 + 3][lrow] = av.w;
        Ws[lk4 + 0][lrow] = wv.x; Ws[lk4 + 1][lrow] = wv.y;
        Ws[lk4 + 2][lrow] = wv.z; Ws[lk4 + 3][lrow] = wv.w;
        __syncthreads();
        #pragma unroll
        for (int kk = 0; kk < 16; ++kk) {
            float4 a = *(const float4*)&As[kk][ty * 4];
            float4 b = *(const float4*)&Ws[kk][tx * 4];
            acc[0][0] += a.x * b.x; acc[0][1] += a.x * b.y; acc[0][2] += a.x * b.z; acc[0][3] += a.x * b.w;
            acc[1][0] += a.y * b.x; acc[1][1] += a.y * b.y; acc[1][2] += a.y * b.z; acc[1][3] += a.y * b.w;
            acc[2][0] += a.z * b.x; acc[2][1] += a.z * b.y; acc[2][2] += a.z * b.z; acc[2][3] += a.z * b.w;
            acc[3][0] += a.w * b.x; acc[3][1] += a.w * b.y; acc[3][2] += a.w * b.z; acc[3][3] += a.w * b.w;
        }
    }

    const int n0 = bn + tx * 4;
    float4 bv = *(const float4*)(gcn_bias + n0);
    float4 b2 = *(const float4*)(gcn_b + n0);
    bv.x += b2.x; bv.y += b2.y; bv.z += b2.z; bv.w += b2.w;

    #pragma unroll
    for (int i = 0; i < 4; ++i) {
        int tk = bm + ty * 4 + i;
        if (tk >= NROW) continue;
        int row_out, half;
        if (tk < BB)                { row_out = tk;                 half = 0; }
        else if (tk < 2 * BB)       { row_out = tk - BB;            half = 1; }
        else if (tk < 2 * BB + FEW) { row_out = BB + tk - 2 * BB;   half = 0; }
        else                        { row_out = BB + tk - 2 * BB - FEW; half = 1; }
        float4 v = make_float4(tanhf(acc[i][0] + bv.x), tanhf(acc[i][1] + bv.y),
                               tanhf(acc[i][2] + bv.z), tanhf(acc[i][3] + bv.w));
        size_t base = (size_t)row_out * 256 + half * 128 + n0;
        *(float4*)(qn2 + base) = v;
        ushort4 u = make_ushort4(f2bf(v.x), f2bf(v.y), f2bf(v.z), f2bf(v.w));
        *(ushort4*)(qn2b + base) = u;
    }
}

// ---------------------------------------------------------------------------
// K4: fused SE-MLP + LayerNorm. One wave per 16 rows (68 blocks x 64 thr).
// GEMM2 covers the full 256-wide row -> LN is wave-local (shfl over l15).
// half-split over h1's 512 cols: GEMM1(K=256,N=256half) -> relu/bf16 ->
// hbuf LDS -> GEMM2 partial accumulate. Block 64 also does support
// mean + l2norm (rows 1024..1028 are local rows 0..4).
// Same bf16 rounding points and MFMA k-order as the unfused version.
// ---------------------------------------------------------------------------
__global__ __launch_bounds__(64) void se_ln_kernel(
    const unsigned short* __restrict__ qn2b, const float* __restrict__ qn2,
    const unsigned short* __restrict__ w1b, const unsigned short* __restrict__ w2b,
    const float* __restrict__ se_b1, const float* __restrict__ se_b2,
    const float* __restrict__ ln_g, const float* __restrict__ ln_b,
    float* __restrict__ qg2, unsigned short* __restrict__ qg2b,
    float* __restrict__ sg0, float* __restrict__ sgn)
{
    __shared__ __align__(16) short hbuf[16][264];  // stride 528B -> 2-way LDS (free)
    __shared__ float sup[5][256];

    const int l = threadIdx.x;           // 0..63, one wave
    const int l15 = l & 15, q = l >> 4;
    const int bm = blockIdx.x * 16;      // 68 blocks * 16 rows = 1088

    floatx4 acc2[16];
    #pragma unroll
    for (int jf = 0; jf < 16; ++jf) acc2[jf] = (floatx4){0.f, 0.f, 0.f, 0.f};

    const unsigned short* Ap = qn2b + (size_t)(bm + l15) * 256 + q * 8;

    for (int half = 0; half < 2; ++half) {
        // GEMM1: h_half[16x256] = qn2b[16x256] @ w1b[half*256..+256, :]^T
        floatx4 h[16];
        #pragma unroll
        for (int jf = 0; jf < 16; ++jf) h[jf] = (floatx4){0.f, 0.f, 0.f, 0.f};
        const unsigned short* Wp = w1b + ((size_t)(half * 256 + l15)) * 256 + q * 8;
        #pragma unroll
        for (int ks = 0; ks < 8; ++ks) {
            short8 a = *(const short8*)(Ap + ks * 32);
            #pragma unroll
            for (int jf = 0; jf < 16; ++jf) {
                short8 b = *(const short8*)(Wp + (size_t)jf * 16 * 256 + ks * 32);
                h[jf] = __builtin_amdgcn_mfma_f32_16x16x32_bf16(a, b, h[jf], 0, 0, 0);
            }
        }
        __syncthreads();
        #pragma unroll
        for (int jf = 0; jf < 16; ++jf) {
            float b1v = se_b1[half * 256 + jf * 16 + l15];
            #pragma unroll
            for (int r = 0; r < 4; ++r)
                hbuf[q * 4 + r][jf * 16 + l15] = (short)f2bf(fmaxf(h[jf][r] + b1v, 0.f));
        }
        __syncthreads();
        // GEMM2 partial: acc2 += h_half @ w2b[:, half*256..+256]^T
        const unsigned short* W2p = w2b + (size_t)l15 * 512 + half * 256 + q * 8;
        #pragma unroll
        for (int ks = 0; ks < 8; ++ks) {
            short8 a = *(const short8*)&hbuf[l15][ks * 32 + q * 8];
            #pragma unroll
            for (int jf = 0; jf < 16; ++jf) {
                short8 b = *(const short8*)(W2p + (size_t)jf * 16 * 512 + ks * 32);
                acc2[jf] = __builtin_amdgcn_mfma_f32_16x16x32_bf16(a, b, acc2[jf], 0, 0, 0);
            }
        }
    }

    // y = acc2 + b2 + residual(qn2); row stats in-register
    float rsum[4] = {0.f, 0.f, 0.f, 0.f}, rqs[4] = {0.f, 0.f, 0.f, 0.f};
    #pragma unroll
    for (int jf = 0; jf < 16; ++jf) {
        int c = jf * 16 + l15;
        float b2v = se_b2[c];
        #pragma unroll
        for (int r = 0; r < 4; ++r) {
            int gm = bm + q * 4 + r;
            float y = acc2[jf][r] + b2v + qn2[(size_t)gm * 256 + c];
            acc2[jf][r] = y;
            rsum[r] += y; rqs[r] += y * y;
        }
    }
    #pragma unroll
    for (int r = 0; r < 4; ++r) {
        #pragma unroll
        for (int m = 1; m < 16; m <<= 1) {
            rsum[r] += __shfl_xor(rsum[r], m, 16);
            rqs[r]  += __shfl_xor(rqs[r],  m, 16);
        }
    }
    float mus[4], invs[4];
    #pragma unroll
    for (int r = 0; r < 4; ++r) {
        float mu  = rsum[r] * (1.0f / 256.0f);
        float var = fmaxf(rqs[r] * (1.0f / 256.0f) - mu * mu, 0.0f);
        mus[r]  = mu;
        invs[r] = 1.0f / sqrtf(var + 1e-5f);
    }
    #pragma unroll
    for (int jf = 0; jf < 16; ++jf) {
        int c = jf * 16 + l15;
        float gv = ln_g[c], bv = ln_b[c];
        #pragma unroll
        for (int r = 0; r < 4; ++r) {
            int gm = bm + q * 4 + r;
            float o = gv * (acc2[jf][r] - mus[r]) * invs[r] + bv;
            if (gm < 1024) {
                qg2 [(size_t)gm * 256 + c] = o;
                qg2b[(size_t)gm * 256 + c] = f2bf(o);
            } else if (gm < 1024 + FEW) {
                sup[gm - 1024][c] = o;
            }
        }
    }
    __syncthreads();
    if (bm == 1024) {           // support mean + l2norm (rows 1024..1028)
        float av[4], qq = 0.f;
        #pragma unroll
        for (int j = 0; j < 4; ++j) {
            int c = l + 64 * j;
            float s = (sup[0][c] + sup[1][c] + sup[2][c] + sup[3][c] + sup[4][c]) * (1.0f / FEW);
            av[j] = s; sg0[c] = s; qq += s * s;
        }
        #pragma unroll
        for (int m = 1; m < 64; m <<= 1) qq += __shfl_xor(qq, m, 64);
        float nrm = fmaxf(sqrtf(qq), 1e-12f);
        #pragma unroll
        for (int j = 0; j < 4; ++j) sgn[l + 64 * j] = av[j] / nrm;
    }
}

// ---------------------------------------------------------------------------
// K5: fully-fused LSTM (was gates1 + step1 + gates2 + step2 = 4 kernels).
// Row-local: block = 16 rows, 4 waves = 4 gate quadrants of N=1024.
// gates1 MFMA (K=256) -> LDS quadrant exchange -> step1 (c1,h1 in regs) ->
// hr tile bf16 in LDS (aliases buf0) -> gates2 MFMA accumulate (K=512) ->
// two-pass exchange -> step2 + l2norm-dot epilogue. No global gates/hr/c1.
// ---------------------------------------------------------------------------
__global__ __launch_bounds__(256) void lstm_kernel(
    const unsigned short* __restrict__ qg2b, const float* __restrict__ qg2,
    const unsigned short* __restrict__ wihb, const unsigned short* __restrict__ whhb,
    const float* __restrict__ bias_c, const float* __restrict__ sg0,
    const float* __restrict__ sgn, float* __restrict__ outv)
{
    __shared__ __align__(16) float buf0[16][264];   // i | hr(bf16 [16][520]) alias
    __shared__ __align__(16) float buf1[16][264];   // g | i2 | g2
    __shared__ __align__(16) float buf2[16][264];   // o | f2 | o2

    const int t = threadIdx.x;
    const int w = t >> 6, l = t & 63;
    const int l15 = l & 15, q = l >> 4;
    const int bm = blockIdx.x * 16;     // 64 blocks * 16 rows = 1024

    floatx4 acc[16];
    #pragma unroll
    for (int jf = 0; jf < 16; ++jf) acc[jf] = (floatx4){0.f, 0.f, 0.f, 0.f};

    // gates1 = qg2b @ wihb^T  (wave w owns cols w*256..+255)
    const unsigned short* Ap = qg2b + (size_t)(bm + l15) * 256 + q * 8;
    const unsigned short* Wp = wihb + ((size_t)(w * 256 + l15)) * 256 + q * 8;
    #pragma unroll
    for (int ks = 0; ks < 8; ++ks) {
        short8 a = *(const short8*)(Ap + ks * 32);
        #pragma unroll
        for (int jf = 0; jf < 16; ++jf) {
            short8 b = *(const short8*)(Wp + (size_t)jf * 16 * 256 + ks * 32);
            acc[jf] = __builtin_amdgcn_mfma_f32_16x16x32_bf16(a, b, acc[jf], 0, 0, 0);
        }
    }
    #pragma unroll
    for (int jf = 0; jf < 16; ++jf) {
        float bv = bias_c[w * 256 + jf * 16 + l15];
        #pragma unroll
        for (int r = 0; r < 4; ++r) acc[jf][r] += bv;
    }

    // exchange i,g,o (f not needed for step1: c0 = 0)
    if (w == 0 || w == 2 || w == 3) {
        float (*dst)[264] = (w == 0) ? buf0 : (w == 2) ? buf1 : buf2;
        #pragma unroll
        for (int jf = 0; jf < 16; ++jf)
            #pragma unroll
            for (int r = 0; r < 4; ++r)
                dst[q * 4 + r][jf * 16 + l15] = acc[jf][r];
    }
    __syncthreads();

    // step1: thread t -> row rr, cols kk+16j
    const int rr = t >> 4, kk = t & 15;
    float c1v[16], h1v[16];
    #pragma unroll
    for (int j = 0; j < 16; ++j) {
        int c = kk + 16 * j;
        float iv = buf0[rr][c], gv = buf1[rr][c], ov = buf2[rr][c];
        float cv = sigf(iv) * tanhf(gv);
        c1v[j] = cv;
        h1v[j] = qg2[(size_t)(bm + rr) * 256 + c] + sigf(ov) * tanhf(cv);
    }
    __syncthreads();

    // hr tile (bf16, [16][520] stride -> 2-way LDS on A-frag reads) into buf0
    unsigned short* hrl = (unsigned short*)buf0;
    #pragma unroll
    for (int j = 0; j < 16; ++j) {
        int c = kk + 16 * j;
        hrl[rr * 520 + c]       = f2bf(h1v[j]);
        hrl[rr * 520 + 256 + c] = f2bf(sg0[c]);
    }
    __syncthreads();

    // gates2 accumulate: acc += hr @ whhb^T  (K=512)
    const unsigned short* W2p = whhb + ((size_t)(w * 256 + l15)) * 512 + q * 8;
    #pragma unroll
    for (int ks = 0; ks < 16; ++ks) {
        short8 a = *(const short8*)(hrl + l15 * 520 + ks * 32 + q * 8);
        #pragma unroll
        for (int jf = 0; jf < 16; ++jf) {
            short8 b = *(const short8*)(W2p + (size_t)jf * 16 * 512 + ks * 32);
            acc[jf] = __builtin_amdgcn_mfma_f32_16x16x32_bf16(a, b, acc[jf], 0, 0, 0);
        }
    }
    __syncthreads();

    // step2 exchange pass1: i2 -> buf1, f2 -> buf2
    if (w == 0 || w == 1) {
        float (*dst)[264] = (w == 0) ? buf1 : buf2;
        #pragma unroll
        for (int jf = 0; jf < 16; ++jf)
            #pragma unroll
            for (int r = 0; r < 4; ++r)
                dst[q * 4 + r][jf * 16 + l15] = acc[jf][r];
    }
    __syncthreads();
    float siv[16], scv[16];
    #pragma unroll
    for (int j = 0; j < 16; ++j) {
        int c = kk + 16 * j;
        siv[j] = sigf(buf1[rr][c]);
        scv[j] = sigf(buf2[rr][c]) * c1v[j];
    }
    __syncthreads();
    // pass2: g2 -> buf1, o2 -> buf2
    if (w == 2 || w == 3) {
        float (*dst)[264] = (w == 2) ? buf1 : buf2;
        #pragma unroll
        for (int jf = 0; jf < 16; ++jf)
            #pragma unroll
            for (int r = 0; r < 4; ++r)
                dst[q * 4 + r][jf * 16 + l15] = acc[jf][r];
    }
    __syncthreads();

    float nn = 0.f, dd = 0.f;
    #pragma unroll
    for (int j = 0; j < 16; ++j) {
        int c = kk + 16 * j;
        float cv = scv[j] + siv[j] * tanhf(buf1[rr][c]);
        float h2 = qg2[(size_t)(bm + rr) * 256 + c] + sigf(buf2[rr][c]) * tanhf(cv);
        nn += h2 * h2; dd += h2 * sgn[c];
    }
    #pragma unroll
    for (int m = 1; m < 16; m <<= 1) {
        nn += __shfl_xor(nn, m, 16);
        dd += __shfl_xor(dd, m, 16);
    }
    if (kk == 0) outv[bm + rr] = dd / fmaxf(sqrtf(nn), 1e-12f);
}

extern "C" void kernel_launch(void* const* d_in, const int* in_sizes, int n_in,
                              void* d_out, int out_size, void* d_ws, size_t ws_size,
                              hipStream_t stream)
{
    const int*   query    = (const int*)d_in[0];
    const int*   support  = (const int*)d_in[1];
    const int*   q_l_conn = (const int*)d_in[2];
    const int*   q_r_conn = (const int*)d_in[4];
    const int*   s_l_conn = (const int*)d_in[6];
    const int*   s_r_conn = (const int*)d_in[8];
    const float* emb      = (const float*)d_in[10];
    const float* gcn_W    = (const float*)d_in[11];
    const float* gcn_bias = (const float*)d_in[12];
    const float* gcn_b    = (const float*)d_in[13];
    const float* se_w1    = (const float*)d_in[14];
    const float* se_b1    = (const float*)d_in[15];
    const float* se_w2    = (const float*)d_in[16];
    const float* se_b2    = (const float*)d_in[17];
    const float* ln_g     = (const float*)d_in[18];
    const float* ln_b     = (const float*)d_in[19];
    const float* W_ih     = (const float*)d_in[20];
    const float* W_hh     = (const float*)d_in[21];
    const float* b_ih     = (const float*)d_in[22];
    const float* b_hh     = (const float*)d_in[23];
    float* out = (float*)d_out;

    float* ws     = (float*)d_ws;
    float* qn2    = ws;                    // 1088*256 f
    float* yq     = qn2    + 1088 * 256;   // (unused after fusion)
    float* qg2    = yq     + 1088 * 256;   // 1088*256 f
    float* sg0    = qg2    + 1088 * 256;   // 256
    float* sgn    = sg0    + 256;          // 256
    float* gates  = sgn    + 256;          // (only sims overlay lives here now)
    float* c1     = gates  + 1024 * 1024;  // (unused after fusion)
    float* avgbuf = c1     + 1024 * 256;   // 2112*256 f
    float* bias_c = avgbuf + 2112 * 256;   // 1024 f
    unsigned short* qn2b = (unsigned short*)(bias_c + 1024);  // 1088*256 sh
    unsigned short* h1b  = qn2b + 1088 * 256;                 // (unused)
    unsigned short* qg2b = h1b  + 1088 * 512;                 // 1024*256 sh
    unsigned short* hrb  = qg2b + 1024 * 256;                 // (unused)
    unsigned short* w1b  = hrb  + 1024 * 512;                 // 512*256 sh
    unsigned short* w2b  = w1b  + 512 * 256;                  // 256*512 sh
    unsigned short* wihb = w2b  + 256 * 512;                  // 1024*256 sh
    unsigned short* whhb = wihb + 1024 * 256;                 // 1024*512 sh
    float* sims = gates;   // overlay: sims (411.6k f) dies before LSTM stage

    // 1. front: sims (wave-per-slice gather) + weight convert, one launch
    front_kernel<<<SIMS_BLOCKS + 4100, 256, 0, stream>>>(
        query, support, q_l_conn, q_r_conn, s_l_conn, s_r_conn, emb, sims,
        se_w1, se_w2, W_ih, W_hh, b_ih, b_hh, w1b, w2b, wihb, whhb, bias_c);

    // 2. top-K rank + mean gather -> avgbuf
    rank_avg_kernel<<<NROW, 256, 0, stream>>>(
        query, support, q_l_conn, q_r_conn, s_l_conn, s_r_conn,
        emb, sims, avgbuf);

    // 3. GCN matvec GEMM -> qn2 (f32 + bf16)
    gcn_gemm_kernel<<<dim3(2, 33), 256, 0, stream>>>(
        avgbuf, gcn_W, gcn_bias, gcn_b, qn2, qn2b);

    // 4. fused SE-MLP + LN (+ support mean + l2norm) -> qg2/qg2b/sg0/sgn
    se_ln_kernel<<<68, 64, 0, stream>>>(
        qn2b, qn2, w1b, w2b, se_b1, se_b2, ln_g, ln_b, qg2, qg2b, sg0, sgn);

    // 5. fully-fused LSTM (gates1+step1+gates2+step2+l2norm·dot) -> out
    lstm_kernel<<<64, 256, 0, stream>>>(
        qg2b, qg2, wihb, whhb, bias_c, sg0, sgn, out);
}

// Round 2
// 294.726 us; speedup vs baseline: 1.5017x; 1.5017x over previous
//
#include <hip/hip_runtime.h>
#include <math.h>

#define NEMB 200000
#define MM   200
#define KTOP 32
#define BB   1024
#define FEW  5
#define NROW 2058           // 2*BB + 2*FEW (row,half) tasks

typedef short short8 __attribute__((ext_vector_type(8)));
typedef float floatx4 __attribute__((ext_vector_type(4)));

__device__ __forceinline__ float sigf(float x) { return 1.0f / (1.0f + expf(-x)); }

__device__ __forceinline__ unsigned short f2bf(float x) {   // RNE f32->bf16
    unsigned u = __float_as_uint(x);
    unsigned r = (u + 0x7FFF + ((u >> 16) & 1)) >> 16;
    return (unsigned short)r;
}

// ---------------------------------------------------------------------------
// K_front: (a) blocks [0,NROW): per-row fused sims + top-K rank + mean gather
// -> avgbuf. 4 waves/block, 16 neighbors per wave-iteration, per-neighbor
// similarity math bit-identical to the old wave-per-slice kernel (selection
// exact). sims stays in LDS — no global sims buffer, no rank launch.
// (b) blocks [NROW, NROW+4100): weight conversion fp32->bf16 + LSTM
// gate-compaction remap + bias fold (independent work, fills pipeline head).
// NOTE: emb table stays fp32 — bf16 sims perturbs top-K selection.
// ---------------------------------------------------------------------------
__global__ __launch_bounds__(256) void front_kernel(
    const int* __restrict__ query, const int* __restrict__ support,
    const int* __restrict__ qlc, const int* __restrict__ qrc,
    const int* __restrict__ slc, const int* __restrict__ srrc,
    const float* __restrict__ emb, float* __restrict__ avgbuf,
    const float* __restrict__ se_w1, const float* __restrict__ se_w2,
    const float* __restrict__ W_ih, const float* __restrict__ W_hh,
    const float* __restrict__ b_ih, const float* __restrict__ b_hh,
    unsigned short* __restrict__ w1b, unsigned short* __restrict__ w2b,
    unsigned short* __restrict__ wihb, unsigned short* __restrict__ whhb,
    float* __restrict__ bias_c)
{
    if (blockIdx.x >= NROW) {
        int i = (blockIdx.x - NROW) * 256 + threadIdx.x;
        if (i < 131072) { w1b[i] = f2bf(se_w1[i]); return; }
        i -= 131072;
        if (i < 131072) { w2b[i] = f2bf(se_w2[i]); return; }
        i -= 131072;
        if (i < 262144) {       // W_ih compact: row n <- orig ((n>>8)<<9)|(n&255)
            int n = i >> 8, k = i & 255;
            int nb = ((n >> 8) << 9) | (n & 255);
            wihb[i] = f2bf(W_ih[(size_t)nb * 256 + k]); return;
        }
        i -= 262144;
        if (i < 524288) {
            int n = i >> 9, k = i & 511;
            int nb = ((n >> 8) << 9) | (n & 255);
            whhb[i] = f2bf(W_hh[(size_t)nb * 512 + k]); return;
        }
        i -= 524288;
        if (i < 1024) {
            int nb = ((i >> 8) << 9) | (i & 255);
            bias_c[i] = b_ih[nb] + b_hh[nb];
        }
        return;
    }

    __shared__ float simsL[MM];
    __shared__ int   cids[MM];
    __shared__ int   selr[KTOP], sele[KTOP];
    __shared__ float partial[512];
    __shared__ int   nsel;

    const int t   = threadIdx.x;
    const int blk = blockIdx.x;
    const int w    = t >> 6;
    const int lane = t & 63;
    const int quad = lane >> 2, ql = lane & 3;

    const int* conn; int eid;
    if (blk < BB)                { conn = qlc + blk * (MM * 2);                eid = query[blk * 2]; }
    else if (blk < 2 * BB)       { int b = blk - BB;        conn = qrc + b * (MM * 2);  eid = query[b * 2 + 1]; }
    else if (blk < 2 * BB + FEW) { int r = blk - 2 * BB;    conn = slc + r * (MM * 2);  eid = support[r * 2]; }
    else                         { int r = blk - 2 * BB - FEW; conn = srrc + r * (MM * 2); eid = support[r * 2 + 1]; }

    // center row (each wave loads its own copy; L1-resident)
    const float4* cb = (const float4*)(emb + (size_t)eid * 128);
    float4 cr[8];
    #pragma unroll
    for (int i = 0; i < 8; ++i) cr[i] = cb[i * 4 + ql];
    float csq = 0.f;
    #pragma unroll
    for (int i = 0; i < 8; ++i)
        csq += cr[i].x * cr[i].x + cr[i].y * cr[i].y + cr[i].z * cr[i].z + cr[i].w * cr[i].w;
    csq += __shfl_xor(csq, 1, 4); csq += __shfl_xor(csq, 2, 4);
    const float cn = sqrtf(csq);

    // sims: 64 neighbor-slots per iteration (4 waves x 16 quads), 4 iters
    for (int it = 0; it < 4; ++it) {
        const int  j = it * 64 + w * 16 + quad;
        const bool v = j < MM;
        const int  rid = v ? conn[j * 2 + 1] : 0;
        const float4* eb = (const float4*)(emb + (size_t)rid * 128);
        float num = 0.f, sq = 0.f;
        #pragma unroll
        for (int i = 0; i < 8; ++i) {
            float4 e = eb[i * 4 + ql];
            num += cr[i].x * e.x + cr[i].y * e.y + cr[i].z * e.z + cr[i].w * e.w;
            sq  += e.x * e.x + e.y * e.y + e.z * e.z + e.w * e.w;
        }
        num += __shfl_xor(num, 1, 4); num += __shfl_xor(num, 2, 4);
        sq  += __shfl_xor(sq , 1, 4); sq  += __shfl_xor(sq , 2, 4);
        if (ql == 0 && v) simsL[j] = num / fmaxf(cn * sqrtf(sq), 1e-8f);
    }
    if (t < MM) cids[t] = conn[t * 2 + 1];
    if (t == 0) nsel = 0;
    __syncthreads();

    // rank: top-K with tie-break lower index (float4 scan over LDS sims)
    if (t < MM) {
        float st = simsL[t];
        int cnt = 0;
        #pragma unroll 2
        for (int j4 = 0; j4 < MM / 4; ++j4) {
            float4 s4 = *(const float4*)&simsL[j4 * 4];
            int jb = j4 * 4;
            cnt += (s4.x > st) || (s4.x == st && (jb + 0) < t);
            cnt += (s4.y > st) || (s4.y == st && (jb + 1) < t);
            cnt += (s4.z > st) || (s4.z == st && (jb + 2) < t);
            cnt += (s4.w > st) || (s4.w == st && (jb + 3) < t);
        }
        if (cnt < KTOP) {
            int p = atomicAdd(&nsel, 1);
            selr[p] = conn[t * 2 + 0];
            sele[p] = cids[t];
        }
    }
    __syncthreads();

    // mean gather of selected rel/ent rows -> avgbuf[blk]
    {
        const int slot = t & 127;
        const int hpar = t >> 7;
        const bool isEnt = slot >= 64;
        float2 acc = make_float2(0.f, 0.f);
        for (int s = hpar; s < KTOP; s += 2) {
            int rid = isEnt ? sele[s] : selr[s];
            float2 v = ((const float2*)(emb + (size_t)rid * 128))[slot & 63];
            acc.x += v.x; acc.y += v.y;
        }
        ((float2*)partial)[t] = acc;
    }
    __syncthreads();
    if (t < 128) {
        float2 a = ((float2*)partial)[t];
        float2 b = ((float2*)partial)[t + 128];
        ((float2*)(avgbuf + (size_t)blk * 256))[t] =
            make_float2((a.x + b.x) * (1.0f / KTOP), (a.y + b.y) * (1.0f / KTOP));
    }
}

// ---------------------------------------------------------------------------
// K3: GCN matvec as fp32 GEMM -> qn2 (fp32) + qn2_bf (bf16)
// ---------------------------------------------------------------------------
__global__ __launch_bounds__(256) void gcn_gemm_kernel(
    const float* __restrict__ A, const float* __restrict__ W,
    const float* __restrict__ gcn_bias, const float* __restrict__ gcn_b,
    float* __restrict__ qn2, unsigned short* __restrict__ qn2b)
{
    __shared__ float As[16][68];
    __shared__ float Ws[16][68];
    const int t  = threadIdx.x;
    const int bm = blockIdx.y * 64, bn = blockIdx.x * 64;
    const int tx = t & 15, ty = t >> 4;
    const int lrow = t >> 2, lk4 = (t & 3) * 4;

    const float* Ap = A + (size_t)(bm + lrow) * 256 + lk4;
    const float* Wp = W + (size_t)(bn + lrow) * 256 + lk4;

    float acc[4][4] = {};
    for (int k0 = 0; k0 < 256; k0 += 16) {
        float4 av = *(const float4*)(Ap + k0);
        float4 wv = *(const float4*)(Wp + k0);
        __syncthreads();
        As[lk4 + 0][lrow] = av.x; As[lk4 + 1][lrow] = av.y;
        As[lk4 + 2][lrow] = av.z; As[lk4 + 3][lrow] = av.w;
        Ws[lk4 + 0][lrow] = wv.x; Ws[lk4 + 1][lrow] = wv.y;
        Ws[lk4 + 2][lrow] = wv.z; Ws[lk4 + 3][lrow] = wv.w;
        __syncthreads();
        #pragma unroll
        for (int kk = 0; kk < 16; ++kk) {
            float4 a = *(const float4*)&As[kk][ty * 4];
            float4 b = *(const float4*)&Ws[kk][tx * 4];
            acc[0][0] += a.x * b.x; acc[0][1] += a.x * b.y; acc[0][2] += a.x * b.z; acc[0][3] += a.x * b.w;
            acc[1][0] += a.y * b.x; acc[1][1] += a.y * b.y; acc[1][2] += a.y * b.z; acc[1][3] += a.y * b.w;
            acc[2][0] += a.z * b.x; acc[2][1] += a.z * b.y; acc[2][2] += a.z * b.z; acc[2][3] += a.z * b.w;
            acc[3][0] += a.w * b.x; acc[3][1] += a.w * b.y; acc[3][2] += a.w * b.z; acc[3][3] += a.w * b.w;
        }
    }

    const int n0 = bn + tx * 4;
    float4 bv = *(const float4*)(gcn_bias + n0);
    float4 b2 = *(const float4*)(gcn_b + n0);
    bv.x += b2.x; bv.y += b2.y; bv.z += b2.z; bv.w += b2.w;

    #pragma unroll
    for (int i = 0; i < 4; ++i) {
        int tk = bm + ty * 4 + i;
        if (tk >= NROW) continue;
        int row_out, half;
        if (tk < BB)                { row_out = tk;                 half = 0; }
        else if (tk < 2 * BB)       { row_out = tk - BB;            half = 1; }
        else if (tk < 2 * BB + FEW) { row_out = BB + tk - 2 * BB;   half = 0; }
        else                        { row_out = BB + tk - 2 * BB - FEW; half = 1; }
        float4 v = make_float4(tanhf(acc[i][0] + bv.x), tanhf(acc[i][1] + bv.y),
                               tanhf(acc[i][2] + bv.z), tanhf(acc[i][3] + bv.w));
        size_t base = (size_t)row_out * 256 + half * 128 + n0;
        *(float4*)(qn2 + base) = v;
        ushort4 u = make_ushort4(f2bf(v.x), f2bf(v.y), f2bf(v.z), f2bf(v.w));
        *(ushort4*)(qn2b + base) = u;
    }
}

// ---------------------------------------------------------------------------
// MFMA bf16 GEMM: C[M,N](fp32 or relu->bf16) = A_bf[M,K] @ W_bf[N,K]^T
// (+bias fp32)(+add fp32). 64x64 block tile, 4 waves, 16x16x32 mfma.
// ---------------------------------------------------------------------------
template <bool RELU_BF_OUT, bool HAS_ADD, bool HAS_BIAS>
__global__ __launch_bounds__(256) void mfma_gemm(
    const unsigned short* __restrict__ Abf, const unsigned short* __restrict__ Wbf,
    const float* __restrict__ bias, const float* __restrict__ add,
    float* __restrict__ Cf, unsigned short* __restrict__ Cbf,
    int N_, int K_)
{
    __shared__ short Asl[64][40];   // +8 pad: 2-way LDS conflicts only (free)
    __shared__ short Wsl[64][40];
    const int t = threadIdx.x;
    const int w = t >> 6, l = t & 63;
    const int l15 = l & 15, q = l >> 4;
    const int bm = blockIdx.y * 64, bn = blockIdx.x * 64;

    const int srow = t >> 2, skoff = (t & 3) * 8;
    const unsigned short* Ap = Abf + (size_t)(bm + srow) * K_ + skoff;
    const unsigned short* Wp = Wbf + (size_t)(bn + srow) * K_ + skoff;

    floatx4 acc[4];
    #pragma unroll
    for (int jf = 0; jf < 4; ++jf) acc[jf] = (floatx4){0.f, 0.f, 0.f, 0.f};

    for (int k0 = 0; k0 < K_; k0 += 32) {
        short8 av = *(const short8*)(Ap + k0);
        short8 wv = *(const short8*)(Wp + k0);
        __syncthreads();
        *(short8*)&Asl[srow][skoff] = av;
        *(short8*)&Wsl[srow][skoff] = wv;
        __syncthreads();
        short8 a = *(const short8*)&Asl[w * 16 + l15][q * 8];
        #pragma unroll
        for (int jf = 0; jf < 4; ++jf) {
            short8 b = *(const short8*)&Wsl[jf * 16 + l15][q * 8];
            acc[jf] = __builtin_amdgcn_mfma_f32_16x16x32_bf16(a, b, acc[jf], 0, 0, 0);
        }
    }

    #pragma unroll
    for (int jf = 0; jf < 4; ++jf) {
        const int col = bn + jf * 16 + l15;
        float bv = HAS_BIAS ? bias[col] : 0.f;
        #pragma unroll
        for (int r = 0; r < 4; ++r) {
            const int m = bm + w * 16 + q * 4 + r;
            float v = acc[jf][r] + bv;
            if (HAS_ADD) v += add[(size_t)m * N_ + col];
            if (RELU_BF_OUT) Cbf[(size_t)m * N_ + col] = f2bf(fmaxf(v, 0.f));
            else             Cf [(size_t)m * N_ + col] = v;
        }
    }
}

// ---------------------------------------------------------------------------
// LayerNorm per row (+ qg2_bf write); block 1024: support rows + mean + l2norm
// ---------------------------------------------------------------------------
__global__ __launch_bounds__(256) void ln_kernel(
    const float* __restrict__ y, const float* __restrict__ g,
    const float* __restrict__ beta, float* __restrict__ out,
    unsigned short* __restrict__ outb, float* __restrict__ sg0,
    float* __restrict__ sgn)
{
    __shared__ float rs[4], rq[4];
    const int t = threadIdx.x;
    const int lane = t & 63, wave = t >> 6;

    if (blockIdx.x < 1024) {
        const int row = blockIdx.x;
        float v = y[row * 256 + t];
        float s = v, q = v * v;
        #pragma unroll
        for (int i = 32; i >= 1; i >>= 1) { s += __shfl_xor(s, i, 64); q += __shfl_xor(q, i, 64); }
        if (lane == 0) { rs[wave] = s; rq[wave] = q; }
        __syncthreads();
        float tot  = rs[0] + rs[1] + rs[2] + rs[3];
        float totq = rq[0] + rq[1] + rq[2] + rq[3];
        float mu  = tot * (1.0f / 256.0f);
        float var = fmaxf(totq * (1.0f / 256.0f) - mu * mu, 0.0f);
        float o = g[t] * (v - mu) / sqrtf(var + 1e-5f) + beta[t];
        out[row * 256 + t]  = o;
        outb[row * 256 + t] = f2bf(o);
    } else {
        float acc = 0.f;
        for (int r = 0; r < FEW; ++r) {
            __syncthreads();
            float v = y[(BB + r) * 256 + t];
            float s = v, q = v * v;
            #pragma unroll
            for (int i = 32; i >= 1; i >>= 1) { s += __shfl_xor(s, i, 64); q += __shfl_xor(q, i, 64); }
            if (lane == 0) { rs[wave] = s; rq[wave] = q; }
            __syncthreads();
            float tot  = rs[0] + rs[1] + rs[2] + rs[3];
            float totq = rq[0] + rq[1] + rq[2] + rq[3];
            float mu  = tot * (1.0f / 256.0f);
            float var = fmaxf(totq * (1.0f / 256.0f) - mu * mu, 0.0f);
            acc += g[t] * (v - mu) / sqrtf(var + 1e-5f) + beta[t];
        }
        acc *= (1.0f / FEW);
        sg0[t] = acc;
        __syncthreads();
        float q = acc * acc;
        #pragma unroll
        for (int i = 32; i >= 1; i >>= 1) q += __shfl_xor(q, i, 64);
        if (lane == 0) rq[wave] = q;
        __syncthreads();
        float nrm = sqrtf(rq[0] + rq[1] + rq[2] + rq[3]);
        sgn[t] = acc / fmaxf(nrm, 1e-12f);
    }
}

// gates compact layout: [0:256)=i [256:512)=f [512:768)=g [768:1024)=o
__global__ __launch_bounds__(256) void lstm_step1_kernel(
    const float* __restrict__ gates, const float* __restrict__ qg,
    const float* __restrict__ sg0, float* __restrict__ c1,
    unsigned short* __restrict__ hrb)
{
    const int row = blockIdx.x, t = threadIdx.x;
    const float* gr = gates + row * 1024;
    float iv = gr[t], gv = gr[512 + t], ov = gr[768 + t];
    float cv = sigf(iv) * tanhf(gv);          // c0 = 0 => f-term drops
    c1[row * 256 + t] = cv;
    float hf = sigf(ov) * tanhf(cv);
    hrb[row * 512 + t]       = f2bf(qg[row * 256 + t] + hf);  // h1
    hrb[row * 512 + 256 + t] = f2bf(sg0[t]);                  // r (attn == 1)
}

__global__ __launch_bounds__(256) void lstm_step2_kernel(
    const float* __restrict__ gates, const float* __restrict__ c1,
    const float* __restrict__ qg, const float* __restrict__ sgn,
    float* __restrict__ outv)
{
    __shared__ float rn[4], rd[4];
    const int row = blockIdx.x, t = threadIdx.x;
    const int lane = t & 63, wave = t >> 6;
    const float* gr = gates + row * 1024;
    float iv = gr[t], fv = gr[256 + t], gv = gr[512 + t], ov = gr[768 + t];
    float cv = sigf(fv) * c1[row * 256 + t] + sigf(iv) * tanhf(gv);
    float h2 = qg[row * 256 + t] + sigf(ov) * tanhf(cv);
    float nn = h2 * h2, dd = h2 * sgn[t];
    #pragma unroll
    for (int i = 32; i >= 1; i >>= 1) { nn += __shfl_xor(nn, i, 64); dd += __shfl_xor(dd, i, 64); }
    if (lane == 0) { rn[wave] = nn; rd[wave] = dd; }
    __syncthreads();
    if (t == 0) {
        float n2 = rn[0] + rn[1] + rn[2] + rn[3];
        float dt = rd[0] + rd[1] + rd[2] + rd[3];
        outv[row] = dt / fmaxf(sqrtf(n2), 1e-12f);
    }
}

extern "C" void kernel_launch(void* const* d_in, const int* in_sizes, int n_in,
                              void* d_out, int out_size, void* d_ws, size_t ws_size,
                              hipStream_t stream)
{
    const int*   query    = (const int*)d_in[0];
    const int*   support  = (const int*)d_in[1];
    const int*   q_l_conn = (const int*)d_in[2];
    const int*   q_r_conn = (const int*)d_in[4];
    const int*   s_l_conn = (const int*)d_in[6];
    const int*   s_r_conn = (const int*)d_in[8];
    const float* emb      = (const float*)d_in[10];
    const float* gcn_W    = (const float*)d_in[11];
    const float* gcn_bias = (const float*)d_in[12];
    const float* gcn_b    = (const float*)d_in[13];
    const float* se_w1    = (const float*)d_in[14];
    const float* se_b1    = (const float*)d_in[15];
    const float* se_w2    = (const float*)d_in[16];
    const float* se_b2    = (const float*)d_in[17];
    const float* ln_g     = (const float*)d_in[18];
    const float* ln_b     = (const float*)d_in[19];
    const float* W_ih     = (const float*)d_in[20];
    const float* W_hh     = (const float*)d_in[21];
    const float* b_ih     = (const float*)d_in[22];
    const float* b_hh     = (const float*)d_in[23];
    float* out = (float*)d_out;

    float* ws     = (float*)d_ws;
    float* qn2    = ws;                    // 1088*256 f
    float* yq     = qn2    + 1088 * 256;   // 1088*256 f
    float* qg2    = yq     + 1088 * 256;   // 1088*256 f
    float* sg0    = qg2    + 1088 * 256;   // 256
    float* sgn    = sg0    + 256;          // 256
    float* gates  = sgn    + 256;          // 1024*1024 f
    float* c1     = gates  + 1024 * 1024;  // 1024*256 f
    float* avgbuf = c1     + 1024 * 256;   // 2112*256 f
    float* bias_c = avgbuf + 2112 * 256;   // 1024 f
    unsigned short* qn2b = (unsigned short*)(bias_c + 1024);  // 1088*256 sh
    unsigned short* h1b  = qn2b + 1088 * 256;                 // 1088*512 sh
    unsigned short* qg2b = h1b  + 1088 * 512;                 // 1024*256 sh
    unsigned short* hrb  = qg2b + 1024 * 256;                 // 1024*512 sh
    unsigned short* w1b  = hrb  + 1024 * 512;                 // 512*256 sh
    unsigned short* w2b  = w1b  + 512 * 256;                  // 256*512 sh
    unsigned short* wihb = w2b  + 256 * 512;                  // 1024*256 sh
    unsigned short* whhb = wihb + 1024 * 256;                 // 1024*512 sh

    // 1. front: per-row sims+rank+avg -> avgbuf  ||  weight convert
    front_kernel<<<NROW + 4100, 256, 0, stream>>>(
        query, support, q_l_conn, q_r_conn, s_l_conn, s_r_conn, emb, avgbuf,
        se_w1, se_w2, W_ih, W_hh, b_ih, b_hh, w1b, w2b, wihb, whhb, bias_c);

    // 2. GCN matvec GEMM -> qn2 (f32 + bf16)
    gcn_gemm_kernel<<<dim3(2, 33), 256, 0, stream>>>(
        avgbuf, gcn_W, gcn_bias, gcn_b, qn2, qn2b);

    // 3. SE GEMM1 (MFMA): h1_bf = bf16(relu(qn2 @ w1^T + b1))
    mfma_gemm<true, false, true><<<dim3(8, 17), 256, 0, stream>>>(
        qn2b, w1b, se_b1, nullptr, nullptr, h1b, 512, 256);

    // 4. SE GEMM2 (MFMA): yq = h1 @ w2^T + b2 + qn2
    mfma_gemm<false, true, true><<<dim3(4, 17), 256, 0, stream>>>(
        h1b, w2b, se_b2, qn2, yq, nullptr, 256, 512);

    // 5. LayerNorm -> qg2 (f32 + bf16) (+ support mean + l2norm in block 1024)
    ln_kernel<<<1025, 256, 0, stream>>>(yq, ln_g, ln_b, qg2, qg2b, sg0, sgn);

    // 6. gates = qg2 @ W_ih'^T + (b_ih+b_hh)  (MFMA, gate-compacted)
    mfma_gemm<false, false, true><<<dim3(16, 16), 256, 0, stream>>>(
        qg2b, wihb, bias_c, nullptr, gates, nullptr, 1024, 256);

    // 7. LSTM step 1 (c0=0, h_r0=0) -> c1, hr_bf
    lstm_step1_kernel<<<1024, 256, 0, stream>>>(gates, qg2, sg0, c1, hrb);

    // 8. gates += hr @ W_hh'^T  (MFMA, in-place add)
    mfma_gemm<false, true, false><<<dim3(16, 16), 256, 0, stream>>>(
        hrb, whhb, nullptr, gates, gates, nullptr, 1024, 512);

    // 9. LSTM step 2 + l2norm + dot(support_gn)
    lstm_step2_kernel<<<1024, 256, 0, stream>>>(gates, c1, qg2, sgn, out);
}

// Round 3
// 294.290 us; speedup vs baseline: 1.5040x; 1.0015x over previous
//
#include <hip/hip_runtime.h>
#include <math.h>

#define NEMB 200000
#define MM   200
#define KTOP 32
#define BB   1024
#define FEW  5
#define NROW 2058           // 2*BB + 2*FEW (row,half) tasks

typedef short short8 __attribute__((ext_vector_type(8)));
typedef float floatx4 __attribute__((ext_vector_type(4)));

__device__ __forceinline__ float sigf(float x) { return 1.0f / (1.0f + expf(-x)); }

__device__ __forceinline__ unsigned short f2bf(float x) {   // RNE f32->bf16
    unsigned u = __float_as_uint(x);
    unsigned r = (u + 0x7FFF + ((u >> 16) & 1)) >> 16;
    return (unsigned short)r;
}

// ---------------------------------------------------------------------------
// K_front: (a) blocks [0,NROW): per-row fused sims + top-K rank + mean gather
// -> avgbuf. 4 waves/block. conn staged to LDS (kills the scattered-index
// serial dependency); sims computed 2 slots/quad/pass with all 16 row-loads
// in flight (MLP fix for the 75us latency-bound profile: 1.9TB/s @ 24%).
// Per-slot math bit-identical to round-2 (selection-exact, absmax preserved).
// (b) blocks [NROW, NROW+4100): weight conversion fp32->bf16 + LSTM
// gate-compaction remap + bias fold (independent work, fills pipeline head).
// NOTE: emb table stays fp32 — bf16 sims perturbs top-K selection.
// ---------------------------------------------------------------------------
__global__ __launch_bounds__(256) void front_kernel(
    const int* __restrict__ query, const int* __restrict__ support,
    const int* __restrict__ qlc, const int* __restrict__ qrc,
    const int* __restrict__ slc, const int* __restrict__ srrc,
    const float* __restrict__ emb, float* __restrict__ avgbuf,
    const float* __restrict__ se_w1, const float* __restrict__ se_w2,
    const float* __restrict__ W_ih, const float* __restrict__ W_hh,
    const float* __restrict__ b_ih, const float* __restrict__ b_hh,
    unsigned short* __restrict__ w1b, unsigned short* __restrict__ w2b,
    unsigned short* __restrict__ wihb, unsigned short* __restrict__ whhb,
    float* __restrict__ bias_c)
{
    if (blockIdx.x >= NROW) {
        int i = (blockIdx.x - NROW) * 256 + threadIdx.x;
        if (i < 131072) { w1b[i] = f2bf(se_w1[i]); return; }
        i -= 131072;
        if (i < 131072) { w2b[i] = f2bf(se_w2[i]); return; }
        i -= 131072;
        if (i < 262144) {       // W_ih compact: row n <- orig ((n>>8)<<9)|(n&255)
            int n = i >> 8, k = i & 255;
            int nb = ((n >> 8) << 9) | (n & 255);
            wihb[i] = f2bf(W_ih[(size_t)nb * 256 + k]); return;
        }
        i -= 262144;
        if (i < 524288) {
            int n = i >> 9, k = i & 511;
            int nb = ((n >> 8) << 9) | (n & 255);
            whhb[i] = f2bf(W_hh[(size_t)nb * 512 + k]); return;
        }
        i -= 524288;
        if (i < 1024) {
            int nb = ((i >> 8) << 9) | (i & 255);
            bias_c[i] = b_ih[nb] + b_hh[nb];
        }
        return;
    }

    __shared__ int   connL[MM * 2];
    __shared__ float simsL[MM];
    __shared__ int   cids[MM];
    __shared__ int   selr[KTOP], sele[KTOP];
    __shared__ float partial[512];
    __shared__ int   nsel;

    const int t   = threadIdx.x;
    const int blk = blockIdx.x;
    const int w    = t >> 6;
    const int lane = t & 63;
    const int quad = lane >> 2, ql = lane & 3;

    const int* conn; int eid;
    if (blk < BB)                { conn = qlc + blk * (MM * 2);                eid = query[blk * 2]; }
    else if (blk < 2 * BB)       { int b = blk - BB;        conn = qrc + b * (MM * 2);  eid = query[b * 2 + 1]; }
    else if (blk < 2 * BB + FEW) { int r = blk - 2 * BB;    conn = slc + r * (MM * 2);  eid = support[r * 2]; }
    else                         { int r = blk - 2 * BB - FEW; conn = srrc + r * (MM * 2); eid = support[r * 2 + 1]; }

    // stage conn -> LDS (one coalesced int4 pass; 400 ints)
    if (t < 100) ((int4*)connL)[t] = ((const int4*)conn)[t];

    // center row (each wave loads its own copy; L1-resident)
    const float4* cb = (const float4*)(emb + (size_t)eid * 128);
    float4 cr[8];
    #pragma unroll
    for (int i = 0; i < 8; ++i) cr[i] = cb[i * 4 + ql];
    float csq = 0.f;
    #pragma unroll
    for (int i = 0; i < 8; ++i)
        csq += cr[i].x * cr[i].x + cr[i].y * cr[i].y + cr[i].z * cr[i].z + cr[i].w * cr[i].w;
    csq += __shfl_xor(csq, 1, 4); csq += __shfl_xor(csq, 2, 4);
    const float cn = sqrtf(csq);

    __syncthreads();   // connL ready

    // sims: 2 passes, 2 slots per quad per pass, all 16 row-loads in flight
    #pragma unroll 1
    for (int p = 0; p < 2; ++p) {
        const int ja = p * 64 + w * 16 + quad;          // [0,128) always valid
        const int jb = ja + 128;                        // [128,256)
        const bool vb = jb < MM;
        const int  ra = connL[ja * 2 + 1];
        const int  rb = vb ? connL[jb * 2 + 1] : 0;
        const float4* ea = (const float4*)(emb + (size_t)ra * 128);
        const float4* eb = (const float4*)(emb + (size_t)rb * 128);
        float4 Ea[8], Eb[8];
        #pragma unroll
        for (int i = 0; i < 8; ++i) Ea[i] = ea[i * 4 + ql];
        #pragma unroll
        for (int i = 0; i < 8; ++i) Eb[i] = eb[i * 4 + ql];

        float numa = 0.f, sqa = 0.f;
        #pragma unroll
        for (int i = 0; i < 8; ++i) {
            numa += cr[i].x * Ea[i].x + cr[i].y * Ea[i].y + cr[i].z * Ea[i].z + cr[i].w * Ea[i].w;
            sqa  += Ea[i].x * Ea[i].x + Ea[i].y * Ea[i].y + Ea[i].z * Ea[i].z + Ea[i].w * Ea[i].w;
        }
        float numb = 0.f, sqb = 0.f;
        #pragma unroll
        for (int i = 0; i < 8; ++i) {
            numb += cr[i].x * Eb[i].x + cr[i].y * Eb[i].y + cr[i].z * Eb[i].z + cr[i].w * Eb[i].w;
            sqb  += Eb[i].x * Eb[i].x + Eb[i].y * Eb[i].y + Eb[i].z * Eb[i].z + Eb[i].w * Eb[i].w;
        }
        numa += __shfl_xor(numa, 1, 4); numa += __shfl_xor(numa, 2, 4);
        sqa  += __shfl_xor(sqa , 1, 4); sqa  += __shfl_xor(sqa , 2, 4);
        numb += __shfl_xor(numb, 1, 4); numb += __shfl_xor(numb, 2, 4);
        sqb  += __shfl_xor(sqb , 1, 4); sqb  += __shfl_xor(sqb , 2, 4);
        if (ql == 0) {
            simsL[ja] = numa / fmaxf(cn * sqrtf(sqa), 1e-8f);
            if (vb) simsL[jb] = numb / fmaxf(cn * sqrtf(sqb), 1e-8f);
        }
    }
    if (t < MM) cids[t] = connL[t * 2 + 1];
    if (t == 0) nsel = 0;
    __syncthreads();

    // rank: top-K with tie-break lower index (float4 scan over LDS sims)
    if (t < MM) {
        float st = simsL[t];
        int cnt = 0;
        #pragma unroll 2
        for (int j4 = 0; j4 < MM / 4; ++j4) {
            float4 s4 = *(const float4*)&simsL[j4 * 4];
            int jb = j4 * 4;
            cnt += (s4.x > st) || (s4.x == st && (jb + 0) < t);
            cnt += (s4.y > st) || (s4.y == st && (jb + 1) < t);
            cnt += (s4.z > st) || (s4.z == st && (jb + 2) < t);
            cnt += (s4.w > st) || (s4.w == st && (jb + 3) < t);
        }
        if (cnt < KTOP) {
            int p = atomicAdd(&nsel, 1);
            selr[p] = connL[t * 2 + 0];
            sele[p] = cids[t];
        }
    }
    __syncthreads();

    // mean gather of selected rel/ent rows -> avgbuf[blk]
    {
        const int slot = t & 127;
        const int hpar = t >> 7;
        const bool isEnt = slot >= 64;
        float2 acc = make_float2(0.f, 0.f);
        for (int s = hpar; s < KTOP; s += 2) {
            int rid = isEnt ? sele[s] : selr[s];
            float2 v = ((const float2*)(emb + (size_t)rid * 128))[slot & 63];
            acc.x += v.x; acc.y += v.y;
        }
        ((float2*)partial)[t] = acc;
    }
    __syncthreads();
    if (t < 128) {
        float2 a = ((float2*)partial)[t];
        float2 b = ((float2*)partial)[t + 128];
        ((float2*)(avgbuf + (size_t)blk * 256))[t] =
            make_float2((a.x + b.x) * (1.0f / KTOP), (a.y + b.y) * (1.0f / KTOP));
    }
}

// ---------------------------------------------------------------------------
// K3: GCN matvec as fp32 GEMM -> qn2 (fp32) + qn2_bf (bf16)
// ---------------------------------------------------------------------------
__global__ __launch_bounds__(256) void gcn_gemm_kernel(
    const float* __restrict__ A, const float* __restrict__ W,
    const float* __restrict__ gcn_bias, const float* __restrict__ gcn_b,
    float* __restrict__ qn2, unsigned short* __restrict__ qn2b)
{
    __shared__ float As[16][68];
    __shared__ float Ws[16][68];
    const int t  = threadIdx.x;
    const int bm = blockIdx.y * 64, bn = blockIdx.x * 64;
    const int tx = t & 15, ty = t >> 4;
    const int lrow = t >> 2, lk4 = (t & 3) * 4;

    const float* Ap = A + (size_t)(bm + lrow) * 256 + lk4;
    const float* Wp = W + (size_t)(bn + lrow) * 256 + lk4;

    float acc[4][4] = {};
    for (int k0 = 0; k0 < 256; k0 += 16) {
        float4 av = *(const float4*)(Ap + k0);
        float4 wv = *(const float4*)(Wp + k0);
        __syncthreads();
        As[lk4 + 0][lrow] = av.x; As[lk4 + 1][lrow] = av.y;
        As[lk4 + 2][lrow] = av.z; As[lk4 + 3][lrow] = av.w;
        Ws[lk4 + 0][lrow] = wv.x; Ws[lk4 + 1][lrow] = wv.y;
        Ws[lk4 + 2][lrow] = wv.z; Ws[lk4 + 3][lrow] = wv.w;
        __syncthreads();
        #pragma unroll
        for (int kk = 0; kk < 16; ++kk) {
            float4 a = *(const float4*)&As[kk][ty * 4];
            float4 b = *(const float4*)&Ws[kk][tx * 4];
            acc[0][0] += a.x * b.x; acc[0][1] += a.x * b.y; acc[0][2] += a.x * b.z; acc[0][3] += a.x * b.w;
            acc[1][0] += a.y * b.x; acc[1][1] += a.y * b.y; acc[1][2] += a.y * b.z; acc[1][3] += a.y * b.w;
            acc[2][0] += a.z * b.x; acc[2][1] += a.z * b.y; acc[2][2] += a.z * b.z; acc[2][3] += a.z * b.w;
            acc[3][0] += a.w * b.x; acc[3][1] += a.w * b.y; acc[3][2] += a.w * b.z; acc[3][3] += a.w * b.w;
        }
    }

    const int n0 = bn + tx * 4;
    float4 bv = *(const float4*)(gcn_bias + n0);
    float4 b2 = *(const float4*)(gcn_b + n0);
    bv.x += b2.x; bv.y += b2.y; bv.z += b2.z; bv.w += b2.w;

    #pragma unroll
    for (int i = 0; i < 4; ++i) {
        int tk = bm + ty * 4 + i;
        if (tk >= NROW) continue;
        int row_out, half;
        if (tk < BB)                { row_out = tk;                 half = 0; }
        else if (tk < 2 * BB)       { row_out = tk - BB;            half = 1; }
        else if (tk < 2 * BB + FEW) { row_out = BB + tk - 2 * BB;   half = 0; }
        else                        { row_out = BB + tk - 2 * BB - FEW; half = 1; }
        float4 v = make_float4(tanhf(acc[i][0] + bv.x), tanhf(acc[i][1] + bv.y),
                               tanhf(acc[i][2] + bv.z), tanhf(acc[i][3] + bv.w));
        size_t base = (size_t)row_out * 256 + half * 128 + n0;
        *(float4*)(qn2 + base) = v;
        ushort4 u = make_ushort4(f2bf(v.x), f2bf(v.y), f2bf(v.z), f2bf(v.w));
        *(ushort4*)(qn2b + base) = u;
    }
}

// ---------------------------------------------------------------------------
// MFMA bf16 GEMM: C[M,N](fp32 or relu->bf16) = A_bf[M,K] @ W_bf[N,K]^T
// (+bias fp32)(+add fp32). 64x64 block tile, 4 waves, 16x16x32 mfma.
// ---------------------------------------------------------------------------
template <bool RELU_BF_OUT, bool HAS_ADD, bool HAS_BIAS>
__global__ __launch_bounds__(256) void mfma_gemm(
    const unsigned short* __restrict__ Abf, const unsigned short* __restrict__ Wbf,
    const float* __restrict__ bias, const float* __restrict__ add,
    float* __restrict__ Cf, unsigned short* __restrict__ Cbf,
    int N_, int K_)
{
    __shared__ short Asl[64][40];   // +8 pad: 2-way LDS conflicts only (free)
    __shared__ short Wsl[64][40];
    const int t = threadIdx.x;
    const int w = t >> 6, l = t & 63;
    const int l15 = l & 15, q = l >> 4;
    const int bm = blockIdx.y * 64, bn = blockIdx.x * 64;

    const int srow = t >> 2, skoff = (t & 3) * 8;
    const unsigned short* Ap = Abf + (size_t)(bm + srow) * K_ + skoff;
    const unsigned short* Wp = Wbf + (size_t)(bn + srow) * K_ + skoff;

    floatx4 acc[4];
    #pragma unroll
    for (int jf = 0; jf < 4; ++jf) acc[jf] = (floatx4){0.f, 0.f, 0.f, 0.f};

    for (int k0 = 0; k0 < K_; k0 += 32) {
        short8 av = *(const short8*)(Ap + k0);
        short8 wv = *(const short8*)(Wp + k0);
        __syncthreads();
        *(short8*)&Asl[srow][skoff] = av;
        *(short8*)&Wsl[srow][skoff] = wv;
        __syncthreads();
        short8 a = *(const short8*)&Asl[w * 16 + l15][q * 8];
        #pragma unroll
        for (int jf = 0; jf < 4; ++jf) {
            short8 b = *(const short8*)&Wsl[jf * 16 + l15][q * 8];
            acc[jf] = __builtin_amdgcn_mfma_f32_16x16x32_bf16(a, b, acc[jf], 0, 0, 0);
        }
    }

    #pragma unroll
    for (int jf = 0; jf < 4; ++jf) {
        const int col = bn + jf * 16 + l15;
        float bv = HAS_BIAS ? bias[col] : 0.f;
        #pragma unroll
        for (int r = 0; r < 4; ++r) {
            const int m = bm + w * 16 + q * 4 + r;
            float v = acc[jf][r] + bv;
            if (HAS_ADD) v += add[(size_t)m * N_ + col];
            if (RELU_BF_OUT) Cbf[(size_t)m * N_ + col] = f2bf(fmaxf(v, 0.f));
            else             Cf [(size_t)m * N_ + col] = v;
        }
    }
}

// ---------------------------------------------------------------------------
// LayerNorm per row (+ qg2_bf write); block 1024: support rows + mean + l2norm
// ---------------------------------------------------------------------------
__global__ __launch_bounds__(256) void ln_kernel(
    const float* __restrict__ y, const float* __restrict__ g,
    const float* __restrict__ beta, float* __restrict__ out,
    unsigned short* __restrict__ outb, float* __restrict__ sg0,
    float* __restrict__ sgn)
{
    __shared__ float rs[4], rq[4];
    const int t = threadIdx.x;
    const int lane = t & 63, wave = t >> 6;

    if (blockIdx.x < 1024) {
        const int row = blockIdx.x;
        float v = y[row * 256 + t];
        float s = v, q = v * v;
        #pragma unroll
        for (int i = 32; i >= 1; i >>= 1) { s += __shfl_xor(s, i, 64); q += __shfl_xor(q, i, 64); }
        if (lane == 0) { rs[wave] = s; rq[wave] = q; }
        __syncthreads();
        float tot  = rs[0] + rs[1] + rs[2] + rs[3];
        float totq = rq[0] + rq[1] + rq[2] + rq[3];
        float mu  = tot * (1.0f / 256.0f);
        float var = fmaxf(totq * (1.0f / 256.0f) - mu * mu, 0.0f);
        float o = g[t] * (v - mu) / sqrtf(var + 1e-5f) + beta[t];
        out[row * 256 + t]  = o;
        outb[row * 256 + t] = f2bf(o);
    } else {
        float acc = 0.f;
        for (int r = 0; r < FEW; ++r) {
            __syncthreads();
            float v = y[(BB + r) * 256 + t];
            float s = v, q = v * v;
            #pragma unroll
            for (int i = 32; i >= 1; i >>= 1) { s += __shfl_xor(s, i, 64); q += __shfl_xor(q, i, 64); }
            if (lane == 0) { rs[wave] = s; rq[wave] = q; }
            __syncthreads();
            float tot  = rs[0] + rs[1] + rs[2] + rs[3];
            float totq = rq[0] + rq[1] + rq[2] + rq[3];
            float mu  = tot * (1.0f / 256.0f);
            float var = fmaxf(totq * (1.0f / 256.0f) - mu * mu, 0.0f);
            acc += g[t] * (v - mu) / sqrtf(var + 1e-5f) + beta[t];
        }
        acc *= (1.0f / FEW);
        sg0[t] = acc;
        __syncthreads();
        float q = acc * acc;
        #pragma unroll
        for (int i = 32; i >= 1; i >>= 1) q += __shfl_xor(q, i, 64);
        if (lane == 0) rq[wave] = q;
        __syncthreads();
        float nrm = sqrtf(rq[0] + rq[1] + rq[2] + rq[3]);
        sgn[t] = acc / fmaxf(nrm, 1e-12f);
    }
}

// gates compact layout: [0:256)=i [256:512)=f [512:768)=g [768:1024)=o
__global__ __launch_bounds__(256) void lstm_step1_kernel(
    const float* __restrict__ gates, const float* __restrict__ qg,
    const float* __restrict__ sg0, float* __restrict__ c1,
    unsigned short* __restrict__ hrb)
{
    const int row = blockIdx.x, t = threadIdx.x;
    const float* gr = gates + row * 1024;
    float iv = gr[t], gv = gr[512 + t], ov = gr[768 + t];
    float cv = sigf(iv) * tanhf(gv);          // c0 = 0 => f-term drops
    c1[row * 256 + t] = cv;
    float hf = sigf(ov) * tanhf(cv);
    hrb[row * 512 + t]       = f2bf(qg[row * 256 + t] + hf);  // h1
    hrb[row * 512 + 256 + t] = f2bf(sg0[t]);                  // r (attn == 1)
}

__global__ __launch_bounds__(256) void lstm_step2_kernel(
    const float* __restrict__ gates, const float* __restrict__ c1,
    const float* __restrict__ qg, const float* __restrict__ sgn,
    float* __restrict__ outv)
{
    __shared__ float rn[4], rd[4];
    const int row = blockIdx.x, t = threadIdx.x;
    const int lane = t & 63, wave = t >> 6;
    const float* gr = gates + row * 1024;
    float iv = gr[t], fv = gr[256 + t], gv = gr[512 + t], ov = gr[768 + t];
    float cv = sigf(fv) * c1[row * 256 + t] + sigf(iv) * tanhf(gv);
    float h2 = qg[row * 256 + t] + sigf(ov) * tanhf(cv);
    float nn = h2 * h2, dd = h2 * sgn[t];
    #pragma unroll
    for (int i = 32; i >= 1; i >>= 1) { nn += __shfl_xor(nn, i, 64); dd += __shfl_xor(dd, i, 64); }
    if (lane == 0) { rn[wave] = nn; rd[wave] = dd; }
    __syncthreads();
    if (t == 0) {
        float n2 = rn[0] + rn[1] + rn[2] + rn[3];
        float dt = rd[0] + rd[1] + rd[2] + rd[3];
        outv[row] = dt / fmaxf(sqrtf(n2), 1e-12f);
    }
}

extern "C" void kernel_launch(void* const* d_in, const int* in_sizes, int n_in,
                              void* d_out, int out_size, void* d_ws, size_t ws_size,
                              hipStream_t stream)
{
    const int*   query    = (const int*)d_in[0];
    const int*   support  = (const int*)d_in[1];
    const int*   q_l_conn = (const int*)d_in[2];
    const int*   q_r_conn = (const int*)d_in[4];
    const int*   s_l_conn = (const int*)d_in[6];
    const int*   s_r_conn = (const int*)d_in[8];
    const float* emb      = (const float*)d_in[10];
    const float* gcn_W    = (const float*)d_in[11];
    const float* gcn_bias = (const float*)d_in[12];
    const float* gcn_b    = (const float*)d_in[13];
    const float* se_w1    = (const float*)d_in[14];
    const float* se_b1    = (const float*)d_in[15];
    const float* se_w2    = (const float*)d_in[16];
    const float* se_b2    = (const float*)d_in[17];
    const float* ln_g     = (const float*)d_in[18];
    const float* ln_b     = (const float*)d_in[19];
    const float* W_ih     = (const float*)d_in[20];
    const float* W_hh     = (const float*)d_in[21];
    const float* b_ih     = (const float*)d_in[22];
    const float* b_hh     = (const float*)d_in[23];
    float* out = (float*)d_out;

    float* ws     = (float*)d_ws;
    float* qn2    = ws;                    // 1088*256 f
    float* yq     = qn2    + 1088 * 256;   // 1088*256 f
    float* qg2    = yq     + 1088 * 256;   // 1088*256 f
    float* sg0    = qg2    + 1088 * 256;   // 256
    float* sgn    = sg0    + 256;          // 256
    float* gates  = sgn    + 256;          // 1024*1024 f
    float* c1     = gates  + 1024 * 1024;  // 1024*256 f
    float* avgbuf = c1     + 1024 * 256;   // 2112*256 f
    float* bias_c = avgbuf + 2112 * 256;   // 1024 f
    unsigned short* qn2b = (unsigned short*)(bias_c + 1024);  // 1088*256 sh
    unsigned short* h1b  = qn2b + 1088 * 256;                 // 1088*512 sh
    unsigned short* qg2b = h1b  + 1088 * 512;                 // 1024*256 sh
    unsigned short* hrb  = qg2b + 1024 * 256;                 // 1024*512 sh
    unsigned short* w1b  = hrb  + 1024 * 512;                 // 512*256 sh
    unsigned short* w2b  = w1b  + 512 * 256;                  // 256*512 sh
    unsigned short* wihb = w2b  + 256 * 512;                  // 1024*256 sh
    unsigned short* whhb = wihb + 1024 * 256;                 // 1024*512 sh

    // 1. front: per-row sims+rank+avg -> avgbuf  ||  weight convert
    front_kernel<<<NROW + 4100, 256, 0, stream>>>(
        query, support, q_l_conn, q_r_conn, s_l_conn, s_r_conn, emb, avgbuf,
        se_w1, se_w2, W_ih, W_hh, b_ih, b_hh, w1b, w2b, wihb, whhb, bias_c);

    // 2. GCN matvec GEMM -> qn2 (f32 + bf16)
    gcn_gemm_kernel<<<dim3(2, 33), 256, 0, stream>>>(
        avgbuf, gcn_W, gcn_bias, gcn_b, qn2, qn2b);

    // 3. SE GEMM1 (MFMA): h1_bf = bf16(relu(qn2 @ w1^T + b1))
    mfma_gemm<true, false, true><<<dim3(8, 17), 256, 0, stream>>>(
        qn2b, w1b, se_b1, nullptr, nullptr, h1b, 512, 256);

    // 4. SE GEMM2 (MFMA): yq = h1 @ w2^T + b2 + qn2
    mfma_gemm<false, true, true><<<dim3(4, 17), 256, 0, stream>>>(
        h1b, w2b, se_b2, qn2, yq, nullptr, 256, 512);

    // 5. LayerNorm -> qg2 (f32 + bf16) (+ support mean + l2norm in block 1024)
    ln_kernel<<<1025, 256, 0, stream>>>(yq, ln_g, ln_b, qg2, qg2b, sg0, sgn);

    // 6. gates = qg2 @ W_ih'^T + (b_ih+b_hh)  (MFMA, gate-compacted)
    mfma_gemm<false, false, true><<<dim3(16, 16), 256, 0, stream>>>(
        qg2b, wihb, bias_c, nullptr, gates, nullptr, 1024, 256);

    // 7. LSTM step 1 (c0=0, h_r0=0) -> c1, hr_bf
    lstm_step1_kernel<<<1024, 256, 0, stream>>>(gates, qg2, sg0, c1, hrb);

    // 8. gates += hr @ W_hh'^T  (MFMA, in-place add)
    mfma_gemm<false, true, false><<<dim3(16, 16), 256, 0, stream>>>(
        hrb, whhb, nullptr, gates, gates, nullptr, 1024, 512);

    // 9. LSTM step 2 + l2norm + dot(support_gn)
    lstm_step2_kernel<<<1024, 256, 0, stream>>>(gates, c1, qg2, sgn, out);
}